// Round 1
// baseline (174.155 us; speedup 1.0000x reference)
//
#include <hip/hip_runtime.h>
#include <hip/hip_bf16.h>

typedef __attribute__((ext_vector_type(8))) short short8;
typedef __attribute__((ext_vector_type(4))) float f32x4;

#define HGT 2048
#define WID 2048
#define NTILES 15625          // 1,000,000 / 64 rows per block
#define WBYTES 44096          // 42 frags * 1024 B + 1088 B biases
#define BIAS_OFF 43008
#define WAVE_BUF 4352         // 16 rows * 272 B
#define LDS_BYTES (WBYTES + 4*WAVE_BUF)   // 61504 <= 64KB static limit
#define ROW_B 272             // bytes per LDS activation row (136 bf16)

__device__ inline unsigned short f2bf_bits(float f){
  union { float f; unsigned int u; } c; c.f = f;
  unsigned int u = c.u;
  return (unsigned short)((u + 0x7fffu + ((u >> 16) & 1u)) >> 16);
}

// ---------------- prepack: weights -> bf16 B-fragment order in d_ws ----------------
// Frag f (1KB each): W1 f=0..7 (nt*2+kk, K=64 eff44), W2 f=8..23 (nt*2+kk),
// W3 f=24..39 (nt*4+kk), W4 f=40..41 (kk). Within frag: lane l (16B) holds
// B[k = kk*32 + (l>>4)*8 + e][col = nt*16 + (l&15)]  (same k-map as A frags).
__global__ void prepack_kernel(const float* __restrict__ W1, const float* __restrict__ b1,
                               const float* __restrict__ W2, const float* __restrict__ b2,
                               const float* __restrict__ W3, const float* __restrict__ b3,
                               const float* __restrict__ W4, const float* __restrict__ b4,
                               unsigned short* __restrict__ packed){
  int tid = blockIdx.x*256 + threadIdx.x;
  if (tid < 42*64) {
    int f = tid >> 6, l = tid & 63;
    int row = l & 15, kgrp = l >> 4;
    int layer, nt, kk;
    if (f < 8)       { layer=1; nt=f>>1;      kk=f&1; }
    else if (f < 24) { layer=2; nt=(f-8)>>1;  kk=(f-8)&1; }
    else if (f < 40) { layer=3; nt=(f-24)>>2; kk=(f-24)&3; }
    else             { layer=4; nt=0;         kk=f-40; }
    unsigned short v16[8];
    #pragma unroll
    for (int e=0;e<8;e++){
      int k = kk*32 + kgrp*8 + e;
      int col = nt*16 + row;
      float v = 0.0f;
      if (layer==1) {
        // collapsed W1': rows 0..35 latent (pixel p=k/4, ch c=k&3 -> orig row p*12+c),
        // rows 36..41 pos (sum over 9 pixels), 42..43 ctrl (sum), 44..63 zero.
        if (k < 36)      { v = W1[((k>>2)*12 + (k&3))*64 + col]; }
        else if (k < 42) { float s=0.f; for (int p=0;p<9;p++) s += W1[(p*12+4+(k-36))*64 + col]; v=s; }
        else if (k < 44) { float s=0.f; for (int p=0;p<9;p++) s += W1[(p*12+10+(k-42))*64 + col]; v=s; }
      } else if (layer==2) { v = W2[k*128 + col]; }
      else if (layer==3)   { v = W3[k*64 + col]; }
      else                 { v = (col < 4) ? W4[k*4 + col] : 0.0f; }
      v16[e] = f2bf_bits(v);
    }
    unsigned short* dst = packed + (size_t)f*512 + (size_t)l*8;
    #pragma unroll
    for (int e=0;e<8;e++) dst[e] = v16[e];
  }
  int bt = tid - 42*64;
  if (bt >= 0 && bt < 272) {
    float v;
    if (bt < 64)       v = b1[bt];
    else if (bt < 192) v = b2[bt-64];
    else if (bt < 256) v = b3[bt-192];
    else               v = (bt-256 < 4) ? b4[bt-256] : 0.0f;
    ((float*)((char*)packed + BIAS_OFF))[bt] = v;
  }
}

// ---------------- activation funcs ----------------
__device__ inline float fast_gelu(float x){
  // tanh-form GELU, exp2 domain: z = 2*log2e*0.7978845608*(x + 0.044715 x^3)
  float x2 = x*x;
  float z  = x * fmaf(0.10294913f, x2, 2.3021164f);
  float t  = __builtin_amdgcn_exp2f(z);
  float th = fmaf(-2.0f, __builtin_amdgcn_rcpf(t + 1.0f), 1.0f);  // tanh
  float hx = 0.5f*x;
  return fmaf(hx, th, hx);
}
__device__ inline float fast_sigmoid(float x){
  return __builtin_amdgcn_rcpf(1.0f + __builtin_amdgcn_exp2f(-1.442695041f*x));
}

// ---------------- main fused kernel ----------------
__global__ __launch_bounds__(256, 2)
void decoder_kernel(const float* __restrict__ latent, const int* __restrict__ raw_pos,
                    const float* __restrict__ control, const unsigned short* __restrict__ packed,
                    float* __restrict__ out){
  __shared__ __attribute__((aligned(16))) char smem[LDS_BYTES];
  const int tid = threadIdx.x;
  { // cooperative copy of packed weights+biases to LDS
    const f32x4* src = (const f32x4*)packed;
    f32x4* dst = (f32x4*)smem;
    for (int i = tid; i < WBYTES/16; i += 256) dst[i] = src[i];
  }
  __syncthreads();

  const int wave = tid >> 6;
  const int lane = tid & 63;
  char* hb = smem + WBYTES + wave*WAVE_BUF;      // wave-private X/H buffer
  const short8* Wfrag = (const short8*)smem;     // Wfrag[f*64 + lane]
  const float* bias = (const float*)(smem + BIAS_OFF);
  const int row4 = lane >> 2;   // build row 0..15
  const int part = lane & 3;    // 4 lanes per row
  const int arow = lane & 15;   // MFMA A-row / C-col
  const int agrp = lane >> 4;   // MFMA k-group / C row-group
  const int arow_b = arow*ROW_B;

  for (int tile = blockIdx.x; tile < NTILES; tile += gridDim.x) {
    const int R0 = tile*64 + wave*16;
    asm volatile("s_waitcnt lgkmcnt(0)" ::: "memory");  // prior-tile LDS reads drained
    // ---------- build X tile (16 x 64 bf16; cols 0..35 latent, 36..43 pos+ctl, 44..63 zero) ----------
    {
      const int prow = R0 + row4;
      const int2 xy = ((const int2*)raw_pos)[prow];
      char* xrow = hb + row4*ROW_B;
      if (part < 3) {
        const int ey = min(max(xy.y + part - 1, 0), HGT-1);
        const float* lrow = latent + (size_t)ey * (WID*4);
        #pragma unroll
        for (int j=0;j<3;j++){
          const int ex = min(max(xy.x + j - 1, 0), WID-1);
          const float4 lv = *(const float4*)(lrow + (size_t)ex*4);
          uint2 pk;
          pk.x = (unsigned)f2bf_bits(lv.x) | ((unsigned)f2bf_bits(lv.y) << 16);
          pk.y = (unsigned)f2bf_bits(lv.z) | ((unsigned)f2bf_bits(lv.w) << 16);
          *(uint2*)(xrow + (part*3+j)*8) = pk;      // pixel p=part*3+j -> cols p*4..p*4+3
        }
        // re-zero pad cols 44..67 (bytes 88..135); parts 0..2 cover 16B each
        uint2 z; z.x = 0u; z.y = 0u;
        *(uint2*)(xrow + 88 + part*16) = z;
        *(uint2*)(xrow + 96 + part*16) = z;
      } else {
        const float xs = (float)min(max(xy.x,0),WID-1) * (1.0f/WID);
        const float ys = (float)min(max(xy.y,0),HGT-1) * (1.0f/HGT);
        float sx,cx,sy,cy;
        __sincosf(6.283185307179586f*xs, &sx, &cx);
        __sincosf(6.283185307179586f*ys, &sy, &cy);
        const float2 ct = ((const float2*)control)[prow];
        uint2 pa, pb;
        pa.x = (unsigned)f2bf_bits(xs) | ((unsigned)f2bf_bits(ys) << 16);
        pa.y = (unsigned)f2bf_bits(sx) | ((unsigned)f2bf_bits(cx) << 16);
        pb.x = (unsigned)f2bf_bits(sy) | ((unsigned)f2bf_bits(cy) << 16);
        pb.y = (unsigned)f2bf_bits(ct.x) | ((unsigned)f2bf_bits(ct.y) << 16);
        *(uint2*)(xrow + 72) = pa;   // cols 36..39
        *(uint2*)(xrow + 80) = pb;   // cols 40..43
      }
    }
    asm volatile("s_waitcnt lgkmcnt(0) vmcnt(0)" ::: "memory");

    // ---------- L1: X(16x64) @ W1'(64x64) ----------
    short8 a0 = *(const short8*)(hb + arow_b + agrp*16);
    short8 a1 = *(const short8*)(hb + arow_b + 64 + agrp*16);
    f32x4 acc[8];
    #pragma unroll
    for (int nt=0;nt<4;nt++){
      f32x4 c = {0.f,0.f,0.f,0.f};
      c = __builtin_amdgcn_mfma_f32_16x16x32_bf16(a0, Wfrag[(nt*2+0)*64 + lane], c, 0,0,0);
      c = __builtin_amdgcn_mfma_f32_16x16x32_bf16(a1, Wfrag[(nt*2+1)*64 + lane], c, 0,0,0);
      acc[nt] = c;
    }
    #pragma unroll
    for (int nt=0;nt<4;nt++){
      const float bv = bias[nt*16 + arow];
      #pragma unroll
      for (int j=0;j<4;j++){
        const float h = fast_gelu(acc[nt][j] + bv);
        *(__hip_bfloat16*)(hb + (agrp*4+j)*ROW_B + (nt*16+arow)*2) = __float2bfloat16(h);
      }
    }
    asm volatile("s_waitcnt lgkmcnt(0)" ::: "memory");

    // ---------- L2: H1(16x64) @ W2(64x128) ----------
    a0 = *(const short8*)(hb + arow_b + agrp*16);
    a1 = *(const short8*)(hb + arow_b + 64 + agrp*16);
    #pragma unroll
    for (int nt=0;nt<8;nt++){
      f32x4 c = {0.f,0.f,0.f,0.f};
      c = __builtin_amdgcn_mfma_f32_16x16x32_bf16(a0, Wfrag[(8+nt*2+0)*64 + lane], c, 0,0,0);
      c = __builtin_amdgcn_mfma_f32_16x16x32_bf16(a1, Wfrag[(8+nt*2+1)*64 + lane], c, 0,0,0);
      acc[nt] = c;
    }
    #pragma unroll
    for (int nt=0;nt<8;nt++){
      const float bv = bias[64 + nt*16 + arow];
      #pragma unroll
      for (int j=0;j<4;j++){
        const float h = fast_gelu(acc[nt][j] + bv);
        *(__hip_bfloat16*)(hb + (agrp*4+j)*ROW_B + (nt*16+arow)*2) = __float2bfloat16(h);
      }
    }
    asm volatile("s_waitcnt lgkmcnt(0)" ::: "memory");

    // ---------- L3: H2(16x128) @ W3(128x64) ----------
    short8 h0 = *(const short8*)(hb + arow_b +   0 + agrp*16);
    short8 h1 = *(const short8*)(hb + arow_b +  64 + agrp*16);
    short8 h2 = *(const short8*)(hb + arow_b + 128 + agrp*16);
    short8 h3 = *(const short8*)(hb + arow_b + 192 + agrp*16);
    #pragma unroll
    for (int nt=0;nt<4;nt++){
      f32x4 c = {0.f,0.f,0.f,0.f};
      c = __builtin_amdgcn_mfma_f32_16x16x32_bf16(h0, Wfrag[(24+nt*4+0)*64 + lane], c, 0,0,0);
      c = __builtin_amdgcn_mfma_f32_16x16x32_bf16(h1, Wfrag[(24+nt*4+1)*64 + lane], c, 0,0,0);
      c = __builtin_amdgcn_mfma_f32_16x16x32_bf16(h2, Wfrag[(24+nt*4+2)*64 + lane], c, 0,0,0);
      c = __builtin_amdgcn_mfma_f32_16x16x32_bf16(h3, Wfrag[(24+nt*4+3)*64 + lane], c, 0,0,0);
      acc[nt] = c;
    }
    #pragma unroll
    for (int nt=0;nt<4;nt++){
      const float bv = bias[192 + nt*16 + arow];
      #pragma unroll
      for (int j=0;j<4;j++){
        const float h = fast_gelu(acc[nt][j] + bv);
        *(__hip_bfloat16*)(hb + (agrp*4+j)*ROW_B + (nt*16+arow)*2) = __float2bfloat16(h);
      }
    }
    asm volatile("s_waitcnt lgkmcnt(0)" ::: "memory");

    // ---------- L4: H3(16x64) @ W4(64x16 pad; cols 0..3 valid) + sigmoid ----------
    a0 = *(const short8*)(hb + arow_b + agrp*16);
    a1 = *(const short8*)(hb + arow_b + 64 + agrp*16);
    f32x4 c4 = {0.f,0.f,0.f,0.f};
    c4 = __builtin_amdgcn_mfma_f32_16x16x32_bf16(a0, Wfrag[40*64 + lane], c4, 0,0,0);
    c4 = __builtin_amdgcn_mfma_f32_16x16x32_bf16(a1, Wfrag[41*64 + lane], c4, 0,0,0);
    if (arow < 4) {
      const float bv = bias[256 + arow];
      #pragma unroll
      for (int j=0;j<4;j++){
        out[(size_t)(R0 + agrp*4 + j)*4 + arow] = fast_sigmoid(c4[j] + bv);
      }
    }
  }
}

extern "C" void kernel_launch(void* const* d_in, const int* in_sizes, int n_in,
                              void* d_out, int out_size, void* d_ws, size_t ws_size,
                              hipStream_t stream) {
  const float* latent  = (const float*)d_in[0];
  const int*   raw_pos = (const int*)d_in[1];
  const float* control = (const float*)d_in[2];
  const float* W1 = (const float*)d_in[3];
  const float* b1 = (const float*)d_in[4];
  const float* W2 = (const float*)d_in[5];
  const float* b2 = (const float*)d_in[6];
  const float* W3 = (const float*)d_in[7];
  const float* b3 = (const float*)d_in[8];
  const float* W4 = (const float*)d_in[9];
  const float* b4 = (const float*)d_in[10];
  unsigned short* packed = (unsigned short*)d_ws;

  prepack_kernel<<<12, 256, 0, stream>>>(W1,b1,W2,b2,W3,b3,W4,b4,packed);
  decoder_kernel<<<1024, 256, 0, stream>>>(latent, raw_pos, control, packed, (float*)d_out);
}

// Round 4
// 120.027 us; speedup vs baseline: 1.4510x; 1.4510x over previous
//
#include <hip/hip_runtime.h>
#include <hip/hip_fp16.h>

typedef __attribute__((ext_vector_type(8))) _Float16 half8;
typedef __attribute__((ext_vector_type(4))) float f32x4;

#define HGT 2048
#define WID 2048
#define NPTS 1000000
#define NTILES 7813           // ceil(1e6 / 128 rows per block)
#define WBYTES 44096          // 42 frags * 1024 B + 1088 B biases
#define BIAS_OFF 43008
#define WAVE_BUF 4352         // 16 rows * 272 B
#define LDS_BYTES (WBYTES + 8*WAVE_BUF)   // 78912 (dynamic LDS, 2 blocks/CU)
#define ROW_B 272             // bytes per LDS activation row (136 f16)

// ---------------- prepack: weights -> f16 fragment order in d_ws ----------------
// Frag f (1KB each): W1 f=0..7 (mt*2+kk, K=64 eff44), W2 f=8..23 (mt*2+kk),
// W3 f=24..39 (mt*4+kk), W4 f=40..41 (kk). Within frag: lane l (16B) holds
// W[k = kk*32 + (l>>4)*8 + e][fout = mt*16 + (l&15)]  == (W^T) A-fragment.
__global__ void prepack_kernel(const float* __restrict__ W1, const float* __restrict__ b1,
                               const float* __restrict__ W2, const float* __restrict__ b2,
                               const float* __restrict__ W3, const float* __restrict__ b3,
                               const float* __restrict__ W4, const float* __restrict__ b4,
                               unsigned short* __restrict__ packed){
  int tid = blockIdx.x*256 + threadIdx.x;
  if (tid < 42*64) {
    int f = tid >> 6, l = tid & 63;
    int row = l & 15, kgrp = l >> 4;
    int layer, nt, kk;
    if (f < 8)       { layer=1; nt=f>>1;      kk=f&1; }
    else if (f < 24) { layer=2; nt=(f-8)>>1;  kk=(f-8)&1; }
    else if (f < 40) { layer=3; nt=(f-24)>>2; kk=(f-24)&3; }
    else             { layer=4; nt=0;         kk=f-40; }
    unsigned short v16[8];
    #pragma unroll
    for (int e=0;e<8;e++){
      int k = kk*32 + kgrp*8 + e;
      int col = nt*16 + row;
      float v = 0.0f;
      if (layer==1) {
        // collapsed W1': rows 0..35 latent (pixel p=k/4, ch c=k&3 -> orig row p*12+c),
        // rows 36..41 pos (sum over 9 pixels), 42..43 ctrl (sum), 44..63 zero.
        if (k < 36)      { v = W1[((k>>2)*12 + (k&3))*64 + col]; }
        else if (k < 42) { float s=0.f; for (int p=0;p<9;p++) s += W1[(p*12+4+(k-36))*64 + col]; v=s; }
        else if (k < 44) { float s=0.f; for (int p=0;p<9;p++) s += W1[(p*12+10+(k-42))*64 + col]; v=s; }
      } else if (layer==2) { v = W2[k*128 + col]; }
      else if (layer==3)   { v = W3[k*64 + col]; }
      else                 { v = (col < 4) ? W4[k*4 + col] : 0.0f; }
      v16[e] = __half_as_ushort(__float2half(v));
    }
    unsigned short* dst = packed + (size_t)f*512 + (size_t)l*8;
    #pragma unroll
    for (int e=0;e<8;e++) dst[e] = v16[e];
  }
  int bt = tid - 42*64;
  if (bt >= 0 && bt < 272) {
    float v;
    if (bt < 64)       v = b1[bt];
    else if (bt < 192) v = b2[bt-64];
    else if (bt < 256) v = b3[bt-192];
    else               v = (bt-256 < 4) ? b4[bt-256] : 0.0f;
    ((float*)((char*)packed + BIAS_OFF))[bt] = v;
  }
}

// ---------------- activation funcs ----------------
// packed-f16 tanh-form GELU: gelu(x) = x * (1 - 1/(1 + 2^z)), z = x*(2.3021 + 0.10295 x^2)
__device__ inline unsigned gelu2_bits(float a, float b){
  __half2 x = __builtin_bit_cast(__half2, __builtin_amdgcn_cvt_pkrtz(a, b));
  const __half2 c0  = __float2half2_rn(2.3021164f);
  const __half2 c1  = __float2half2_rn(0.10294913f);
  const __half2 one = __float2half2_rn(1.0f);
  __half2 x2 = __hmul2(x, x);
  __half2 z  = __hmul2(x, __hfma2(c1, x2, c0));
  __half2 t  = h2exp2(z);                    // t=inf for large x -> r=0 -> gelu=x; t=0 -> gelu=0
  __half2 r  = h2rcp(__hadd2(t, one));
  __half2 res = __hmul2(x, __hsub2(one, r));
  return __builtin_bit_cast(unsigned, res);
}
__device__ inline float fast_sigmoid(float x){
  return __builtin_amdgcn_rcpf(1.0f + __builtin_amdgcn_exp2f(-1.442695041f*x));
}

// one MLP layer, transposed chain: C = W^T_tile (A) x H^T (B); output features along
// register axis j -> contiguous row-major LDS writes (cvt_pkrtz pairs, b64 stores).
template<int MT, int KT, int FB, int BO>
__device__ inline void layer_fwd(const half8* __restrict__ Wfrag, const float* __restrict__ bias,
                                 char* hb, int nlo, int g, int lane){
  half8 bx[KT];
  #pragma unroll
  for (int kk=0; kk<KT; kk++)
    bx[kk] = *(const half8*)(hb + nlo*ROW_B + kk*64 + g*16);
  #pragma unroll
  for (int mt=0; mt<MT; mt++){
    f32x4 c = {0.f,0.f,0.f,0.f};
    #pragma unroll
    for (int kk=0; kk<KT; kk++)
      c = __builtin_amdgcn_mfma_f32_16x16x32_f16(Wfrag[(FB + mt*KT + kk)*64 + lane], bx[kk], c, 0,0,0);
    const f32x4 bv = *(const f32x4*)(bias + BO + mt*16 + g*4);
    uint2 w;
    w.x = gelu2_bits(c[0]+bv[0], c[1]+bv[1]);
    w.y = gelu2_bits(c[2]+bv[2], c[3]+bv[3]);
    *(uint2*)(hb + nlo*ROW_B + (mt*16 + g*4)*2) = w;   // features mt*16+g*4..+3 of point nlo
  }
}

// ---------------- main fused kernel ----------------
__global__ __launch_bounds__(512, 4)
void decoder_kernel(const float* __restrict__ latent, const int* __restrict__ raw_pos,
                    const float* __restrict__ control, const unsigned short* __restrict__ packed,
                    float* __restrict__ out){
  extern __shared__ __attribute__((aligned(16))) char smem[];
  const int tid = threadIdx.x;
  { // cooperative copy of packed weights+biases to LDS (shared by 8 waves)
    const f32x4* src = (const f32x4*)packed;
    f32x4* dst = (f32x4*)smem;
    for (int i = tid; i < WBYTES/16; i += 512) dst[i] = src[i];
    // zero pad cols 44..63 (bytes 88..127) of ALL 128 activation rows ONCE.
    // Tile 0 then reads exact zeros; later tiles read stale finite H2 values
    // which hit the zero rows 44..63 of W1' -> contribution exactly 0.0.
    // (NaN bug fix: uninitialized LDS here could be inf/NaN -> 0*inf = NaN in MFMA.)
    for (int i = tid; i < 128*5; i += 512) {
      int row = i / 5, p = i % 5;
      uint2 z; z.x = 0u; z.y = 0u;
      *(uint2*)(smem + WBYTES + (row>>4)*WAVE_BUF + (row&15)*ROW_B + 88 + p*8) = z;
    }
  }
  __syncthreads();

  const int wave = tid >> 6;
  const int lane = tid & 63;
  char* hb = smem + WBYTES + wave*WAVE_BUF;      // wave-private X/H buffer (16 rows x 272 B)
  const half8* Wfrag = (const half8*)smem;       // Wfrag[f*64 + lane]
  const float* bias = (const float*)(smem + BIAS_OFF);
  const int row4 = lane >> 2;   // build row 0..15
  const int part = lane & 3;    // 4 lanes per row
  const int nlo  = lane & 15;   // MFMA B-col = point row; C-col
  const int g    = lane >> 4;   // MFMA k-group / C row-group

  for (int tile = blockIdx.x; tile < NTILES; tile += gridDim.x) {
    const int R0 = tile*128 + wave*16;
    if (R0 >= NPTS) continue;
    asm volatile("s_waitcnt lgkmcnt(0)" ::: "memory");
    // ---------- build X tile (16 x 64 f16; cols 0..35 latent, 36..43 pos+ctl, 44..63 zero) ----------
    {
      const int prow = R0 + row4;
      const int2 xy = ((const int2*)raw_pos)[prow];
      char* xrow = hb + row4*ROW_B;
      if (part < 3) {
        const int ey = min(max(xy.y + part - 1, 0), HGT-1);
        const float* lrow = latent + (size_t)ey * (WID*4);
        #pragma unroll
        for (int j=0;j<3;j++){
          const int ex = min(max(xy.x + j - 1, 0), WID-1);
          const float4 lv = *(const float4*)(lrow + (size_t)ex*4);
          uint2 pk;
          pk.x = __builtin_bit_cast(unsigned, __builtin_amdgcn_cvt_pkrtz(lv.x, lv.y));
          pk.y = __builtin_bit_cast(unsigned, __builtin_amdgcn_cvt_pkrtz(lv.z, lv.w));
          *(uint2*)(xrow + (part*3+j)*8) = pk;      // pixel p=part*3+j -> cols p*4..p*4+3
        }
      } else {
        const float xs = (float)min(max(xy.x,0),WID-1) * (1.0f/WID);
        const float ys = (float)min(max(xy.y,0),HGT-1) * (1.0f/HGT);
        const float sx = __builtin_amdgcn_sinf(xs);  // v_sin_f32: input in revolutions = sin(2*pi*xs)
        const float cx = __builtin_amdgcn_cosf(xs);
        const float sy = __builtin_amdgcn_sinf(ys);
        const float cy = __builtin_amdgcn_cosf(ys);
        const float2 ct = ((const float2*)control)[prow];
        uint2 pa, pb;
        pa.x = __builtin_bit_cast(unsigned, __builtin_amdgcn_cvt_pkrtz(xs, ys));
        pa.y = __builtin_bit_cast(unsigned, __builtin_amdgcn_cvt_pkrtz(sx, cx));
        pb.x = __builtin_bit_cast(unsigned, __builtin_amdgcn_cvt_pkrtz(sy, cy));
        pb.y = __builtin_bit_cast(unsigned, __builtin_amdgcn_cvt_pkrtz(ct.x, ct.y));
        *(uint2*)(xrow + 72) = pa;   // cols 36..39
        *(uint2*)(xrow + 80) = pb;   // cols 40..43
      }
    }
    asm volatile("s_waitcnt lgkmcnt(0) vmcnt(0)" ::: "memory");

    layer_fwd<4, 2, 0,   0>(Wfrag, bias, hb, nlo, g, lane);   // L1: 64 -> 64
    asm volatile("s_waitcnt lgkmcnt(0)" ::: "memory");
    layer_fwd<8, 2, 8,  64>(Wfrag, bias, hb, nlo, g, lane);   // L2: 64 -> 128
    asm volatile("s_waitcnt lgkmcnt(0)" ::: "memory");
    layer_fwd<4, 4, 24, 192>(Wfrag, bias, hb, nlo, g, lane);  // L3: 128 -> 64
    asm volatile("s_waitcnt lgkmcnt(0)" ::: "memory");

    // ---------- L4: (64 -> 4) + sigmoid; C[m=j][n=point], valid g==0 ----------
    {
      half8 bx0 = *(const half8*)(hb + nlo*ROW_B +  0 + g*16);
      half8 bx1 = *(const half8*)(hb + nlo*ROW_B + 64 + g*16);
      f32x4 c = {0.f,0.f,0.f,0.f};
      c = __builtin_amdgcn_mfma_f32_16x16x32_f16(Wfrag[40*64 + lane], bx0, c, 0,0,0);
      c = __builtin_amdgcn_mfma_f32_16x16x32_f16(Wfrag[41*64 + lane], bx1, c, 0,0,0);
      const f32x4 bv = *(const f32x4*)(bias + 256 + g*4);
      if (g == 0) {
        f32x4 o;
        #pragma unroll
        for (int j=0;j<4;j++) o[j] = fast_sigmoid(c[j] + bv[j]);
        *(f32x4*)(out + (size_t)(R0 + nlo)*4) = o;
      }
    }
  }
}

extern "C" void kernel_launch(void* const* d_in, const int* in_sizes, int n_in,
                              void* d_out, int out_size, void* d_ws, size_t ws_size,
                              hipStream_t stream) {
  const float* latent  = (const float*)d_in[0];
  const int*   raw_pos = (const int*)d_in[1];
  const float* control = (const float*)d_in[2];
  const float* W1 = (const float*)d_in[3];
  const float* b1 = (const float*)d_in[4];
  const float* W2 = (const float*)d_in[5];
  const float* b2 = (const float*)d_in[6];
  const float* W3 = (const float*)d_in[7];
  const float* b3 = (const float*)d_in[8];
  const float* W4 = (const float*)d_in[9];
  const float* b4 = (const float*)d_in[10];
  unsigned short* packed = (unsigned short*)d_ws;

  static bool attr_set = false;
  if (!attr_set) {
    (void)hipFuncSetAttribute((const void*)decoder_kernel,
                              hipFuncAttributeMaxDynamicSharedMemorySize, LDS_BYTES);
    attr_set = true;
  }

  prepack_kernel<<<12, 256, 0, stream>>>(W1,b1,W2,b2,W3,b3,W4,b4,packed);
  decoder_kernel<<<1024, 512, LDS_BYTES, stream>>>(latent, raw_pos, control, packed, (float*)d_out);
}

// Round 5
// 109.302 us; speedup vs baseline: 1.5933x; 1.0981x over previous
//
#include <hip/hip_runtime.h>
#include <hip/hip_fp16.h>

typedef __attribute__((ext_vector_type(8))) _Float16 half8;
typedef __attribute__((ext_vector_type(4))) float f32x4;
typedef __attribute__((ext_vector_type(4))) unsigned int uint4v;

#define HGT 2048
#define WID 2048
#define NPTS 1000000
#define NTILES 3907           // ceil(1e6 / 256 points per block-iter)
#define WBYTES 44096          // 42 frags * 1024 B + 1088 B biases
#define BIAS_OFF 43008

// Feature-slot permutation maps (see theory): producer c-slot feeding k-slot k.
__device__ __host__ inline int c64map(int k){   // 64-feature producer
  return 16*(k>>5) + 32*((k&7)>>2) + 4*((k>>3)&3) + (k&3);
}
__device__ __host__ inline int c128map(int k){  // 128-feature producer
  return 16*(k>>5) + 64*((k&7)>>2) + 4*((k>>3)&3) + (k&3);
}

// ---------------- prepack: weights -> f16 A-fragment order in d_ws ----------------
// Frag f (1KB): W1 f=0..7 (mt*2+kk), W2 f=8..23 (mt*2+kk), W3 f=24..39 (mt*4+kk),
// W4 f=40..41 (kk). Lane l holds W_stored[k = kk*32 + (l>>4)*8 + e][fout = mt*16 + (l&15)].
// Consumer rows are PERMUTED via c64map/c128map so inter-layer transpose is free.
__global__ void prepack_kernel(const float* __restrict__ W1, const float* __restrict__ b1,
                               const float* __restrict__ W2, const float* __restrict__ b2,
                               const float* __restrict__ W3, const float* __restrict__ b3,
                               const float* __restrict__ W4, const float* __restrict__ b4,
                               unsigned short* __restrict__ packed){
  int tid = blockIdx.x*256 + threadIdx.x;
  if (tid < 42*64) {
    int f = tid >> 6, l = tid & 63;
    int fr = l & 15, kg = l >> 4;
    int layer, mt, kk;
    if (f < 8)       { layer=1; mt=f>>1;      kk=f&1; }
    else if (f < 24) { layer=2; mt=(f-8)>>1;  kk=(f-8)&1; }
    else if (f < 40) { layer=3; mt=(f-24)>>2; kk=(f-24)&3; }
    else             { layer=4; mt=0;         kk=f-40; }
    unsigned short v16[8];
    #pragma unroll
    for (int e=0;e<8;e++){
      int k = kk*32 + kg*8 + e;
      int fout = mt*16 + fr;
      float v = 0.0f;
      if (layer==1) {
        // X k-slots: k<36 pixel k>>2 chan k&3; 36..41 pos-sum ch; 42..43 ctl-sum ch; else 0
        if (k < 36)      { v = W1[((k>>2)*12 + (k&3))*64 + fout]; }
        else if (k < 42) { float s=0.f; for (int p=0;p<9;p++) s += W1[(p*12+4+(k-36))*64 + fout]; v=s; }
        else if (k < 44) { float s=0.f; for (int p=0;p<9;p++) s += W1[(p*12+10+(k-42))*64 + fout]; v=s; }
      } else if (layer==2) { v = W2[c64map(k)*128 + fout]; }
      else if (layer==3)   { v = W3[c128map(k)*64 + fout]; }
      else                 { v = (fr < 4) ? W4[c64map(k)*4 + fr] : 0.0f; }
      v16[e] = __half_as_ushort(__float2half(v));
    }
    unsigned short* dst = packed + (size_t)f*512 + (size_t)l*8;
    #pragma unroll
    for (int e=0;e<8;e++) dst[e] = v16[e];
  }
  int bt = tid - 42*64;
  if (bt >= 0 && bt < 272) {
    float v;
    if (bt < 64)       v = b1[bt];
    else if (bt < 192) v = b2[bt-64];
    else if (bt < 256) v = b3[bt-192];
    else               v = (bt-256 < 4) ? b4[bt-256] : 0.0f;
    ((float*)((char*)packed + BIAS_OFF))[bt] = v;
  }
}

// ---------------- helpers ----------------
__device__ inline unsigned pkf(float a, float b){
  return __builtin_bit_cast(unsigned, __builtin_amdgcn_cvt_pkrtz(a, b));
}
// packed-f16 tanh-form GELU: gelu(x) = x * (1 - 1/(1 + 2^z)), z = x*(2.3021 + 0.10295 x^2)
__device__ inline unsigned gelu2_bits(float a, float b){
  __half2 x = __builtin_bit_cast(__half2, __builtin_amdgcn_cvt_pkrtz(a, b));
  const __half2 c0  = __float2half2_rn(2.3021164f);
  const __half2 c1  = __float2half2_rn(0.10294913f);
  const __half2 one = __float2half2_rn(1.0f);
  __half2 x2 = __hmul2(x, x);
  __half2 z  = __hmul2(x, __hfma2(c1, x2, c0));
  __half2 t  = h2exp2(z);
  __half2 r  = h2rcp(__hadd2(t, one));
  __half2 res = __hmul2(x, __hsub2(one, r));
  return __builtin_bit_cast(unsigned, res);
}
__device__ inline float fast_sigmoid(float x){
  return __builtin_amdgcn_rcpf(1.0f + __builtin_amdgcn_exp2f(-1.442695041f*x));
}
__device__ inline half8 mk8(uint2 a, uint2 b){
  uint4v t; t.x = a.x; t.y = a.y; t.z = b.x; t.w = b.y;
  return __builtin_bit_cast(half8, t);
}

// One layer for TWO 16-point groups sharing each weight-frag read (J=2).
// C-in = bias (free bias add). Output u[mt] = packed f16 pairs (j01, j23).
template<int MT,int KT,int FB,int BO>
__device__ inline void layer2(const half8* __restrict__ Wfrag, const float* __restrict__ bias,
                              const half8* bxa, const half8* bxb,
                              uint2* ua, uint2* ub, int lane, int g){
  #pragma unroll
  for (int mt=0; mt<MT; mt++){
    const f32x4 bv = *(const f32x4*)(bias + BO + mt*16 + g*4);
    f32x4 a = bv, b = bv;
    #pragma unroll
    for (int kk=0; kk<KT; kk++){
      const half8 w = Wfrag[(FB + mt*KT + kk)*64 + lane];
      a = __builtin_amdgcn_mfma_f32_16x16x32_f16(w, bxa[kk], a, 0,0,0);
      b = __builtin_amdgcn_mfma_f32_16x16x32_f16(w, bxb[kk], b, 0,0,0);
    }
    ua[mt].x = gelu2_bits(a[0], a[1]); ua[mt].y = gelu2_bits(a[2], a[3]);
    ub[mt].x = gelu2_bits(b[0], b[1]); ub[mt].y = gelu2_bits(b[2], b[3]);
  }
}

// ---------------- main fused kernel: registers-only dataflow ----------------
__global__ __launch_bounds__(512, 6)
void decoder_kernel(const float* __restrict__ latent, const int* __restrict__ raw_pos,
                    const float* __restrict__ control, const unsigned short* __restrict__ packed,
                    float* __restrict__ out){
  __shared__ __attribute__((aligned(16))) char smem[WBYTES];
  const int tid = threadIdx.x;
  { // cooperative copy of packed weights+biases to LDS (shared by 8 waves)
    const f32x4* src = (const f32x4*)packed;
    f32x4* dst = (f32x4*)smem;
    for (int i = tid; i < WBYTES/16; i += 512) dst[i] = src[i];
  }
  __syncthreads();

  const half8* Wfrag = (const half8*)smem;
  const float* bias  = (const float*)(smem + BIAS_OFF);
  const int wave = tid >> 6, lane = tid & 63;
  const int nlo = lane & 15, g = lane >> 4;
  // per-lane gather offsets for pixels 2g, 2g+1 (dx = p%3-1, dy = p/3-1)
  const int pA = g*2, pB = g*2+1;
  const int qA = (pA>=3) + (pA>=6), qB = (pB>=3) + (pB>=6);
  const int dyA = qA-1, dxA = pA-3*qA-1;
  const int dyB = qB-1, dxB = pB-3*qB-1;

  for (int tile = blockIdx.x; tile < NTILES; tile += gridDim.x){
    const int R0 = tile*256 + wave*32;
    if (R0 >= NPTS) continue;

    // ---------- build L1 B-frags for two point groups, per-lane direct gather ----------
    half8 bx[2][2];
    #pragma unroll
    for (int jj=0; jj<2; jj++){
      const int prow = R0 + jj*16 + nlo;
      const int2 xy = ((const int2*)raw_pos)[prow];
      const int exA = min(max(xy.x + dxA, 0), WID-1);
      const int eyA = min(max(xy.y + dyA, 0), HGT-1);
      const int exB = min(max(xy.x + dxB, 0), WID-1);
      const int eyB = min(max(xy.y + dyB, 0), HGT-1);
      const f32x4 lA = *(const f32x4*)(latent + ((size_t)eyA*WID + exA)*4);
      const f32x4 lB = *(const f32x4*)(latent + ((size_t)eyB*WID + exB)*4);
      uint4v f0;
      f0.x = pkf(lA[0], lA[1]); f0.y = pkf(lA[2], lA[3]);
      f0.z = pkf(lB[0], lB[1]); f0.w = pkf(lB[2], lB[3]);
      bx[jj][0] = __builtin_bit_cast(half8, f0);

      const float xs = (float)xy.x * (1.0f/WID), ys = (float)xy.y * (1.0f/HGT);
      const float sx = __builtin_amdgcn_sinf(xs), cx = __builtin_amdgcn_cosf(xs);
      const float sy = __builtin_amdgcn_sinf(ys), cy = __builtin_amdgcn_cosf(ys);
      uint4v f1; f1.x = 0u; f1.y = 0u; f1.z = 0u; f1.w = 0u;
      if (g == 0){
        const int ex8 = min(xy.x + 1, WID-1), ey8 = min(xy.y + 1, HGT-1);
        const f32x4 l8 = *(const f32x4*)(latent + ((size_t)ey8*WID + ex8)*4);
        f1.x = pkf(l8[0], l8[1]); f1.y = pkf(l8[2], l8[3]);
        f1.z = pkf(xs, ys); f1.w = pkf(sx, cx);
      } else if (g == 1){
        const float2 ct = ((const float2*)control)[prow];
        f1.x = pkf(sy, cy); f1.y = pkf(ct.x, ct.y);
      }
      bx[jj][1] = __builtin_bit_cast(half8, f1);
    }

    // ---------- MLP chain, activations live entirely in registers ----------
    uint2 u0[8], u1[8];
    half8 ha[4], hb[4];
    layer2<4,2,0,0>(Wfrag, bias, bx[0], bx[1], u0, u1, lane, g);          // L1: 64->64
    ha[0]=mk8(u0[0],u0[2]); ha[1]=mk8(u0[1],u0[3]);
    hb[0]=mk8(u1[0],u1[2]); hb[1]=mk8(u1[1],u1[3]);
    layer2<8,2,8,64>(Wfrag, bias, ha, hb, u0, u1, lane, g);               // L2: 64->128
    ha[0]=mk8(u0[0],u0[4]); ha[1]=mk8(u0[1],u0[5]);
    ha[2]=mk8(u0[2],u0[6]); ha[3]=mk8(u0[3],u0[7]);
    hb[0]=mk8(u1[0],u1[4]); hb[1]=mk8(u1[1],u1[5]);
    hb[2]=mk8(u1[2],u1[6]); hb[3]=mk8(u1[3],u1[7]);
    layer2<4,4,24,192>(Wfrag, bias, ha, hb, u0, u1, lane, g);             // L3: 128->64
    ha[0]=mk8(u0[0],u0[2]); ha[1]=mk8(u0[1],u0[3]);
    hb[0]=mk8(u1[0],u1[2]); hb[1]=mk8(u1[1],u1[3]);

    // ---------- L4: 64->4 + sigmoid ----------
    const f32x4 bv4 = *(const f32x4*)(bias + 256 + g*4);
    f32x4 a = bv4, b = bv4;
    #pragma unroll
    for (int kk=0; kk<2; kk++){
      const half8 w = Wfrag[(40+kk)*64 + lane];
      a = __builtin_amdgcn_mfma_f32_16x16x32_f16(w, ha[kk], a, 0,0,0);
      b = __builtin_amdgcn_mfma_f32_16x16x32_f16(w, hb[kk], b, 0,0,0);
    }
    if (g == 0){
      f32x4 oa, ob;
      #pragma unroll
      for (int j=0;j<4;j++){ oa[j] = fast_sigmoid(a[j]); ob[j] = fast_sigmoid(b[j]); }
      *(f32x4*)(out + (size_t)(R0 + nlo)*4)      = oa;
      *(f32x4*)(out + (size_t)(R0 + 16 + nlo)*4) = ob;
    }
  }
}

extern "C" void kernel_launch(void* const* d_in, const int* in_sizes, int n_in,
                              void* d_out, int out_size, void* d_ws, size_t ws_size,
                              hipStream_t stream) {
  const float* latent  = (const float*)d_in[0];
  const int*   raw_pos = (const int*)d_in[1];
  const float* control = (const float*)d_in[2];
  const float* W1 = (const float*)d_in[3];
  const float* b1 = (const float*)d_in[4];
  const float* W2 = (const float*)d_in[5];
  const float* b2 = (const float*)d_in[6];
  const float* W3 = (const float*)d_in[7];
  const float* b3 = (const float*)d_in[8];
  const float* W4 = (const float*)d_in[9];
  const float* b4 = (const float*)d_in[10];
  unsigned short* packed = (unsigned short*)d_ws;

  prepack_kernel<<<12, 256, 0, stream>>>(W1,b1,W2,b2,W3,b3,W4,b4,packed);
  decoder_kernel<<<NTILES, 512, 0, stream>>>(latent, raw_pos, control, packed, (float*)d_out);
}